// Round 1
// baseline (92.723 us; speedup 1.0000x reference)
//
#include <hip/hip_runtime.h>
#include <hip/hip_bf16.h>
#include <stdint.h>

typedef __attribute__((ext_vector_type(4))) int   i32x4;
typedef __attribute__((ext_vector_type(8))) int   i32x8;
typedef __attribute__((ext_vector_type(4))) float f32x4;

#define MDIM   4096
#define NDIM   4096
#define KBYTES 2048   // K=4096 fp4 elems -> 2048 packed bytes per row
#define NKBLK  128    // K/32 scale blocks per row

#define BM   128
#define BN   128
#define BKB  128                 // K-bytes per step (= 256 fp4 elems = 8 scale blocks)
#define KSTEPS (KBYTES / BKB)    // 16

// ---------------- repack: int32-per-byte -> packed bytes ----------------
__global__ void repack_bytes(const int* __restrict__ a, const int* __restrict__ b,
                             uint32_t* __restrict__ ap, uint32_t* __restrict__ bp) {
  const size_t n4 = (size_t)MDIM * KBYTES / 4;  // 2M output dwords per matrix
  for (size_t i = (size_t)blockIdx.x * blockDim.x + threadIdx.x; i < n4;
       i += (size_t)gridDim.x * blockDim.x) {
    i32x4 va = *(const i32x4*)(a + i * 4);
    ap[i] = (uint32_t)(va.x & 255) | ((uint32_t)(va.y & 255) << 8) |
            ((uint32_t)(va.z & 255) << 16) | ((uint32_t)(va.w & 255) << 24);
    i32x4 vb = *(const i32x4*)(b + i * 4);
    bp[i] = (uint32_t)(vb.x & 255) | ((uint32_t)(vb.y & 255) << 8) |
            ((uint32_t)(vb.z & 255) << 16) | ((uint32_t)(vb.w & 255) << 24);
  }
}

// ---------------- scales: float biased-exp -> uint8 E8M0, transposed [kb][row] ---
__global__ void repack_scales(const float* __restrict__ sa, const float* __restrict__ sb,
                              uint8_t* __restrict__ sat, uint8_t* __restrict__ sbt) {
  int t = blockIdx.x * blockDim.x + threadIdx.x;
  if (t >= MDIM * NKBLK) return;
  int m = t >> 7;      // row
  int kb = t & 127;    // k-block
  sat[kb * MDIM + m] = (uint8_t)(int)sa[t];
  sbt[kb * NDIM + m] = (uint8_t)(int)sb[t];
}

__device__ __forceinline__ i32x8 frag8(i32x4 v) {
  i32x8 r = {v.x, v.y, v.z, v.w, 0, 0, 0, 0};
  return r;
}

// ---------------- MXFP4 GEMM: C[m][n] = sum_k A[m,k]*B[n,k] ----------------
__global__ __launch_bounds__(256) void mxfp4_gemm(
    const uint8_t* __restrict__ ap, const uint8_t* __restrict__ bp,
    const uint8_t* __restrict__ sat, const uint8_t* __restrict__ sbt,
    float* __restrict__ out) {
  __shared__ __align__(16) uint8_t lA[BM * BKB];  // 16 KB, xor-swizzled slots
  __shared__ __align__(16) uint8_t lB[BN * BKB];  // 16 KB

  const int tid  = threadIdx.x;
  const int lane = tid & 63;
  const int w    = tid >> 6;        // wave 0..3
  const int wrow = w >> 1;          // 2x2 wave grid, each wave does 64x64
  const int wcol = w & 1;
  const int g    = lane >> 4;       // k-group 0..3 (32 fp4 elems each)
  const int l15  = lane & 15;
  const int lx   = lane & 7;        // read-side xor term (== row&7 for our rows)

  const int bx = blockIdx.x;        // n tile
  const int by = blockIdx.y;        // m tile

  const uint8_t* aBase = ap + (size_t)(by * BM) * KBYTES;
  const uint8_t* bBase = bp + (size_t)(bx * BN) * KBYTES;

  // staging: each global_load_lds writes 1KB = 8 rows x 128B, linear LDS dest.
  // source slot is pre-swizzled so LDS[row][s] holds global slot s^(row&7).
  const int srow  = lane >> 3;              // 0..7 within the 8-row group
  const int sslot = (lane & 7) ^ srow;      // inverse (== same) involution
  const int soff  = srow * KBYTES + sslot * 16;

  f32x4 acc[4][4] = {};

  for (int ks = 0; ks < KSTEPS; ++ks) {
    const int k0 = ks * BKB;
#pragma unroll
    for (int q = 0; q < 4; ++q) {
      const int r0 = (w * 4 + q) * 8;       // first row of this 1KB chunk
      __builtin_amdgcn_global_load_lds(
          (__attribute__((address_space(1))) void*)(aBase + (size_t)r0 * KBYTES + k0 + soff),
          (__attribute__((address_space(3))) void*)(lA + (w * 4 + q) * 1024),
          16, 0, 0);
      __builtin_amdgcn_global_load_lds(
          (__attribute__((address_space(1))) void*)(bBase + (size_t)r0 * KBYTES + k0 + soff),
          (__attribute__((address_space(3))) void*)(lB + (w * 4 + q) * 1024),
          16, 0, 0);
    }
    __syncthreads();   // drains vmcnt before barrier -> staging complete

    const int kbBase = ks * 8;              // absolute scale-block base this step
#pragma unroll
    for (int kw = 0; kw < 2; ++kw) {        // two K=128 mfma chunks per step
      const int slotx = ((kw * 4 + g) ^ lx) * 16;
      i32x4 af[4], bf[4];
      int   sA[4], sB[4];
#pragma unroll
      for (int ms = 0; ms < 4; ++ms) {
        const int row = wrow * 64 + ms * 16 + l15;
        af[ms] = *(const i32x4*)(lA + row * BKB + slotx);
        sA[ms] = sat[(kbBase + kw * 4 + g) * MDIM + by * BM + row];
      }
#pragma unroll
      for (int ns = 0; ns < 4; ++ns) {
        const int row = wcol * 64 + ns * 16 + l15;
        bf[ns] = *(const i32x4*)(lB + row * BKB + slotx);
        sB[ns] = sbt[(kbBase + kw * 4 + g) * NDIM + bx * BN + row];
      }
#pragma unroll
      for (int ms = 0; ms < 4; ++ms)
#pragma unroll
        for (int ns = 0; ns < 4; ++ns)
          acc[ms][ns] = __builtin_amdgcn_mfma_scale_f32_16x16x128_f8f6f4(
              frag8(af[ms]), frag8(bf[ns]), acc[ms][ns],
              4 /*cbsz: FP4*/, 4 /*blgp: FP4*/,
              0, sA[ms], 0, sB[ns]);
    }
    __syncthreads();   // all reads done before next staging overwrites LDS
  }

  // epilogue: D lane mapping (16x16 shapes): row=(lane>>4)*4+r, col=lane&15
  float* ob = out + (size_t)(by * BM + wrow * 64) * NDIM + bx * BN + wcol * 64;
#pragma unroll
  for (int ms = 0; ms < 4; ++ms)
#pragma unroll
    for (int ns = 0; ns < 4; ++ns) {
#pragma unroll
      for (int r = 0; r < 4; ++r)
        ob[(size_t)(ms * 16 + g * 4 + r) * NDIM + ns * 16 + l15] = acc[ms][ns][r];
    }
}

extern "C" void kernel_launch(void* const* d_in, const int* in_sizes, int n_in,
                              void* d_out, int out_size, void* d_ws, size_t ws_size,
                              hipStream_t stream) {
  (void)in_sizes; (void)n_in; (void)out_size; (void)ws_size;
  const int*   a  = (const int*)d_in[0];
  const int*   b  = (const int*)d_in[1];
  const float* sa = (const float*)d_in[2];
  const float* sb = (const float*)d_in[3];
  float* out = (float*)d_out;

  uint8_t* ws = (uint8_t*)d_ws;
  uint32_t* ap = (uint32_t*)ws;                          // 8 MB packed A
  uint32_t* bp = (uint32_t*)(ws + (8u << 20));           // 8 MB packed B
  uint8_t*  sat = ws + (16u << 20);                      // 512 KB scales A^T
  uint8_t*  sbt = ws + (16u << 20) + (512u << 10);       // 512 KB scales B^T

  repack_bytes<<<2048, 256, 0, stream>>>(a, b, ap, bp);
  repack_scales<<<(MDIM * NKBLK + 255) / 256, 256, 0, stream>>>(sa, sb, sat, sbt);

  dim3 grid(NDIM / BN, MDIM / BM);
  mxfp4_gemm<<<grid, 256, 0, stream>>>((const uint8_t*)ap, (const uint8_t*)bp,
                                       sat, sbt, out);
}